// Round 1
// baseline (187.466 us; speedup 1.0000x reference)
//
#include <hip/hip_runtime.h>

#define EDIM 256
#define HDIM 256

__device__ __forceinline__ float waveAllSum(float v) {
  #pragma unroll
  for (int m = 32; m >= 1; m >>= 1) v += __shfl_xor(v, m, 64);
  return v;
}

// ---------------------------------------------------------------------------
// K1: six row-matmuls (128 rows each): P/Q projections for rel-encode (both
// sides) and CA/CB for corr score. Biases folded: rel_b1 -> P, cor_b1 -> CB.
// ---------------------------------------------------------------------------
__global__ __launch_bounds__(256) void k_proj(
    const float* __restrict__ srcE, const float* __restrict__ tgtE,
    const float* __restrict__ relW1, const float* __restrict__ relb1,
    const float* __restrict__ corW1, const float* __restrict__ corb1,
    float* __restrict__ Ps, float* __restrict__ Qs,
    float* __restrict__ Pt, float* __restrict__ Qt,
    float* __restrict__ CA, float* __restrict__ CB)
{
  const int which = blockIdx.y;   // 0..5
  const int row   = blockIdx.x;   // 0..127  (b*16 + i)
  const int h     = threadIdx.x;

  const float* A; const float* W; const float* bias; float* out;
  if (which == 0)      { A = srcE; W = relW1;              bias = relb1;   out = Ps; }
  else if (which == 1) { A = srcE; W = relW1 + EDIM*HDIM;  bias = nullptr; out = Qs; }
  else if (which == 2) { A = tgtE; W = relW1;              bias = relb1;   out = Pt; }
  else if (which == 3) { A = tgtE; W = relW1 + EDIM*HDIM;  bias = nullptr; out = Qt; }
  else if (which == 4) { A = srcE; W = corW1;              bias = nullptr; out = CA; }
  else                 { A = tgtE; W = corW1 + EDIM*HDIM;  bias = corb1;   out = CB; }

  __shared__ float arow[EDIM];
  arow[h] = A[row*EDIM + h];
  __syncthreads();

  float acc = bias ? bias[h] : 0.0f;
  #pragma unroll 8
  for (int d = 0; d < EDIM; ++d) acc = fmaf(arow[d], W[d*HDIM + h], acc);
  out[row*HDIM + h] = acc;
}

// ---------------------------------------------------------------------------
// K2: fused rel-encode: x = P[b,i,:]+Q[b,j,:]; LN; relu; @rel_W2 + b2; mask.
// One block per (side, b, i, j). Thread = output column k.
// ---------------------------------------------------------------------------
__global__ __launch_bounds__(256) void k_encode(
    const float* __restrict__ Ps, const float* __restrict__ Qs,
    const float* __restrict__ relS, float* __restrict__ outS,
    const float* __restrict__ Pt, const float* __restrict__ Qt,
    const float* __restrict__ relT, float* __restrict__ outT,
    const float* __restrict__ g1, const float* __restrict__ be1,
    const float* __restrict__ W2, const float* __restrict__ b2)
{
  const int side = blockIdx.y;
  const float* P   = side ? Pt   : Ps;
  const float* Q   = side ? Qt   : Qs;
  const float* rel = side ? relT : relS;
  float* out       = side ? outT : outS;

  const int bi = blockIdx.x;          // b*256 + ij
  const int b  = bi >> 8;
  const int ij = bi & 255;
  const int i  = ij >> 4, j = ij & 15;
  const int h  = threadIdx.x;

  const float x = P[(b*16 + i)*HDIM + h] + Q[(b*16 + j)*HDIM + h];

  // block reduce sum & sumsq over 256 threads
  float s1 = x, s2 = x*x;
  #pragma unroll
  for (int m = 32; m >= 1; m >>= 1) { s1 += __shfl_xor(s1, m, 64); s2 += __shfl_xor(s2, m, 64); }
  __shared__ float r1[4], r2[4];
  const int wave = threadIdx.x >> 6;
  if ((threadIdx.x & 63) == 0) { r1[wave] = s1; r2[wave] = s2; }
  __syncthreads();
  s1 = r1[0] + r1[1] + r1[2] + r1[3];
  s2 = r2[0] + r2[1] + r2[2] + r2[3];

  const float mean = s1 * (1.0f/256.0f);
  const float var  = s2 * (1.0f/256.0f) - mean*mean;
  const float rinv = rsqrtf(var + 1e-5f);
  float r = fmaf((x - mean) * rinv, g1[h], be1[h]);
  r = fmaxf(r, 0.0f);

  __shared__ float rl[HDIM];
  rl[h] = r;
  __syncthreads();

  const float mask = (rel[(b*16 + i)*16 + j] > 0.0f) ? 1.0f : 0.0f;
  float acc = b2[h];
  #pragma unroll 8
  for (int k = 0; k < HDIM; ++k) acc = fmaf(rl[k], W2[k*HDIM + h], acc);
  out[(b*256 + ij)*HDIM + h] = acc * mask;
}

// ---------------------------------------------------------------------------
// K3: SA = src_rel @ Wa ; TB = tgt_rel @ Wb + map_b1. 4 rows per block for
// W reuse (cuts L2 traffic of map_W1 4x).
// ---------------------------------------------------------------------------
__global__ __launch_bounds__(256) void k_pairproj(
    const float* __restrict__ srel, const float* __restrict__ trel,
    const float* __restrict__ mapW1, const float* __restrict__ mapb1,
    float* __restrict__ SA, float* __restrict__ TB)
{
  const int which = blockIdx.y;        // 0: SA, 1: TB
  const int r0 = blockIdx.x * 4;       // 2048 rows total
  const int h  = threadIdx.x;

  const float* A = which ? trel : srel;
  const float* W = which ? (mapW1 + EDIM*HDIM) : mapW1;

  __shared__ float arow[4][EDIM];
  #pragma unroll
  for (int r = 0; r < 4; ++r) arow[r][h] = A[(r0 + r)*EDIM + h];
  __syncthreads();

  float acc0, acc1, acc2, acc3;
  acc0 = acc1 = acc2 = acc3 = which ? mapb1[h] : 0.0f;
  #pragma unroll 4
  for (int d = 0; d < EDIM; ++d) {
    const float wv = W[d*HDIM + h];
    acc0 = fmaf(arow[0][d], wv, acc0);
    acc1 = fmaf(arow[1][d], wv, acc1);
    acc2 = fmaf(arow[2][d], wv, acc2);
    acc3 = fmaf(arow[3][d], wv, acc3);
  }
  float* out = which ? TB : SA;
  out[(r0+0)*HDIM + h] = acc0;
  out[(r0+1)*HDIM + h] = acc1;
  out[(r0+2)*HDIM + h] = acc2;
  out[(r0+3)*HDIM + h] = acc3;
}

// ---------------------------------------------------------------------------
// K4: fused mapping score + softmax. Block = (b,s). 4 waves; wave w owns
// t in [64w, 64w+64); lanes split H as float4 (coalesced 1KB row reads).
// LN stats + W2-dot via wave-only shfl butterflies (no barriers in hot loop).
// ---------------------------------------------------------------------------
__global__ __launch_bounds__(256) void k_mapscore(
    const float* __restrict__ SA, const float* __restrict__ TB,
    const float* __restrict__ g, const float* __restrict__ be,
    const float* __restrict__ W2, const float* __restrict__ b2p,
    float* __restrict__ out)
{
  const int bs   = blockIdx.x;         // b*256 + s
  const int b    = bs >> 8;
  const int wave = threadIdx.x >> 6;
  const int lane = threadIdx.x & 63;

  const float4 sa4 = *(const float4*)(SA + bs*HDIM + lane*4);
  const float4 g4  = *(const float4*)(g  + lane*4);
  const float4 be4 = *(const float4*)(be + lane*4);
  const float4 w24 = *(const float4*)(W2 + lane*4);
  const float b2   = b2p[0];
  const float* TBb = TB + b*(256*HDIM);

  float myscore = 0.0f;
  for (int it = 0; it < 64; ++it) {
    const int t = wave*64 + it;
    const float4 tb4 = *(const float4*)(TBb + t*HDIM + lane*4);
    const float x0 = sa4.x + tb4.x, x1 = sa4.y + tb4.y;
    const float x2 = sa4.z + tb4.z, x3 = sa4.w + tb4.w;
    float s1 = x0 + x1 + x2 + x3;
    float s2 = x0*x0 + x1*x1 + x2*x2 + x3*x3;
    #pragma unroll
    for (int m = 32; m >= 1; m >>= 1) { s1 += __shfl_xor(s1, m, 64); s2 += __shfl_xor(s2, m, 64); }
    const float mean = s1 * (1.0f/256.0f);
    const float var  = s2 * (1.0f/256.0f) - mean*mean;
    const float rinv = rsqrtf(var + 1e-5f);
    const float r0 = fmaxf(fmaf((x0 - mean)*rinv, g4.x, be4.x), 0.0f);
    const float r1 = fmaxf(fmaf((x1 - mean)*rinv, g4.y, be4.y), 0.0f);
    const float r2 = fmaxf(fmaf((x2 - mean)*rinv, g4.z, be4.z), 0.0f);
    const float r3 = fmaxf(fmaf((x3 - mean)*rinv, g4.w, be4.w), 0.0f);
    float p = r0*w24.x + r1*w24.y + r2*w24.z + r3*w24.w;
    p = waveAllSum(p);
    if (lane == it) myscore = p + b2;   // this thread's t == threadIdx.x
  }

  // softmax over the block's 256 scores (thread's t == threadIdx.x)
  __shared__ float red[8];
  float mx = myscore;
  #pragma unroll
  for (int m = 32; m >= 1; m >>= 1) mx = fmaxf(mx, __shfl_xor(mx, m, 64));
  if (lane == 0) red[wave] = mx;
  __syncthreads();
  mx = fmaxf(fmaxf(red[0], red[1]), fmaxf(red[2], red[3]));
  const float e = __expf(myscore - mx);
  float se = waveAllSum(e);
  if (lane == 0) red[4 + wave] = se;
  __syncthreads();
  se = red[4] + red[5] + red[6] + red[7];
  out[bs*256 + threadIdx.x] = e / se;
}

// ---------------------------------------------------------------------------
// K5: corr score (no LN) + softmax over 16. One wave per (b,s).
// ---------------------------------------------------------------------------
__global__ __launch_bounds__(64) void k_corr(
    const float* __restrict__ CA, const float* __restrict__ CB,
    const float* __restrict__ W2, const float* __restrict__ b2p,
    float* __restrict__ out)
{
  const int bs   = blockIdx.x;    // b*16 + s
  const int b    = bs >> 4;
  const int lane = threadIdx.x;

  const float4 ca4 = *(const float4*)(CA + bs*HDIM + lane*4);
  const float4 w24 = *(const float4*)(W2 + lane*4);
  const float b2   = b2p[0];

  float sc[16];
  #pragma unroll
  for (int t = 0; t < 16; ++t) {
    const float4 cb4 = *(const float4*)(CB + (b*16 + t)*HDIM + lane*4);
    float p = fmaxf(ca4.x + cb4.x, 0.0f)*w24.x
            + fmaxf(ca4.y + cb4.y, 0.0f)*w24.y
            + fmaxf(ca4.z + cb4.z, 0.0f)*w24.z
            + fmaxf(ca4.w + cb4.w, 0.0f)*w24.w;
    p = waveAllSum(p);
    sc[t] = p + b2;
  }
  float mx = sc[0];
  #pragma unroll
  for (int t = 1; t < 16; ++t) mx = fmaxf(mx, sc[t]);
  float se = 0.0f;
  #pragma unroll
  for (int t = 0; t < 16; ++t) { sc[t] = __expf(sc[t] - mx); se += sc[t]; }
  if (lane < 16) out[bs*16 + lane] = sc[lane] / se;
}

extern "C" void kernel_launch(void* const* d_in, const int* in_sizes, int n_in,
                              void* d_out, int out_size, void* d_ws, size_t ws_size,
                              hipStream_t stream) {
  const float* srcE  = (const float*)d_in[0];
  const float* srcR  = (const float*)d_in[1];
  const float* tgtE  = (const float*)d_in[2];
  const float* tgtR  = (const float*)d_in[3];
  const float* relW1 = (const float*)d_in[4];
  const float* relb1 = (const float*)d_in[5];
  const float* relg1 = (const float*)d_in[6];
  const float* relbe1= (const float*)d_in[7];
  const float* relW2 = (const float*)d_in[8];
  const float* relb2 = (const float*)d_in[9];
  const float* mapW1 = (const float*)d_in[10];
  const float* mapb1 = (const float*)d_in[11];
  const float* mapg  = (const float*)d_in[12];
  const float* mapbe = (const float*)d_in[13];
  const float* mapW2 = (const float*)d_in[14];
  const float* mapb2 = (const float*)d_in[15];
  const float* corW1 = (const float*)d_in[16];
  const float* corb1 = (const float*)d_in[17];
  const float* corW2 = (const float*)d_in[18];
  const float* corb2 = (const float*)d_in[19];

  float* ws   = (float*)d_ws;
  float* Ps   = ws;                 // 8*16*256 = 32768 each
  float* Qs   = Ps   + 32768;
  float* Pt   = Qs   + 32768;
  float* Qt   = Pt   + 32768;
  float* CA   = Qt   + 32768;
  float* CB   = CA   + 32768;
  float* srel = CB   + 32768;       // 8*256*256 = 524288 each
  float* trel = srel + 524288;
  float* SA   = trel + 524288;
  float* TB   = SA   + 524288;

  float* mapOut = (float*)d_out;        // 524288
  float* corOut = mapOut + 524288;      // 2048

  k_proj<<<dim3(128, 6), 256, 0, stream>>>(srcE, tgtE, relW1, relb1, corW1, corb1,
                                           Ps, Qs, Pt, Qt, CA, CB);
  k_encode<<<dim3(2048, 2), 256, 0, stream>>>(Ps, Qs, srcR, srel,
                                              Pt, Qt, tgtR, trel,
                                              relg1, relbe1, relW2, relb2);
  k_pairproj<<<dim3(512, 2), 256, 0, stream>>>(srel, trel, mapW1, mapb1, SA, TB);
  k_mapscore<<<2048, 256, 0, stream>>>(SA, TB, mapg, mapbe, mapW2, mapb2, mapOut);
  k_corr<<<128, 64, 0, stream>>>(CA, CB, corW2, corb2, corOut);
}

// Round 2
// 99.944 us; speedup vs baseline: 1.8757x; 1.8757x over previous
//
#include <hip/hip_runtime.h>

#define EDIM 256
#define HDIM 256

__device__ __forceinline__ float waveAllSum(float v) {
  #pragma unroll
  for (int m = 32; m >= 1; m >>= 1) v += __shfl_xor(v, m, 64);
  return v;
}

// ---------------------------------------------------------------------------
// K1: six row-matmuls (128 rows each): P/Q projections for rel-encode (both
// sides) and CA/CB for corr score. Biases folded: rel_b1 -> P, cor_b1 -> CB.
// ---------------------------------------------------------------------------
__global__ __launch_bounds__(256) void k_proj(
    const float* __restrict__ srcE, const float* __restrict__ tgtE,
    const float* __restrict__ relW1, const float* __restrict__ relb1,
    const float* __restrict__ corW1, const float* __restrict__ corb1,
    float* __restrict__ Ps, float* __restrict__ Qs,
    float* __restrict__ Pt, float* __restrict__ Qt,
    float* __restrict__ CA, float* __restrict__ CB)
{
  const int which = blockIdx.y;   // 0..5
  const int row   = blockIdx.x;   // 0..127  (b*16 + i)
  const int h     = threadIdx.x;

  const float* A; const float* W; const float* bias; float* out;
  if (which == 0)      { A = srcE; W = relW1;              bias = relb1;   out = Ps; }
  else if (which == 1) { A = srcE; W = relW1 + EDIM*HDIM;  bias = nullptr; out = Qs; }
  else if (which == 2) { A = tgtE; W = relW1;              bias = relb1;   out = Pt; }
  else if (which == 3) { A = tgtE; W = relW1 + EDIM*HDIM;  bias = nullptr; out = Qt; }
  else if (which == 4) { A = srcE; W = corW1;              bias = nullptr; out = CA; }
  else                 { A = tgtE; W = corW1 + EDIM*HDIM;  bias = corb1;   out = CB; }

  __shared__ float arow[EDIM];
  arow[h] = A[row*EDIM + h];
  __syncthreads();

  float acc = bias ? bias[h] : 0.0f;
  #pragma unroll 8
  for (int d = 0; d < EDIM; ++d) acc = fmaf(arow[d], W[d*HDIM + h], acc);
  out[row*HDIM + h] = acc;
}

// ---------------------------------------------------------------------------
// K2: fused rel-encode, 4 rows (same b,i; consecutive j) per block:
// x = P[b,i,:]+Q[b,j,:]; LN; relu; @rel_W2 + b2; mask. 4x W2 reuse.
// ---------------------------------------------------------------------------
__global__ __launch_bounds__(256) void k_encode(
    const float* __restrict__ Ps, const float* __restrict__ Qs,
    const float* __restrict__ relS, float* __restrict__ outS,
    const float* __restrict__ Pt, const float* __restrict__ Qt,
    const float* __restrict__ relT, float* __restrict__ outT,
    const float* __restrict__ g1, const float* __restrict__ be1,
    const float* __restrict__ W2, const float* __restrict__ b2)
{
  const int side = blockIdx.y;
  const float* P   = side ? Pt   : Ps;
  const float* Q   = side ? Qt   : Qs;
  const float* rel = side ? relT : relS;
  float* out       = side ? outT : outS;

  const int row0 = blockIdx.x * 4;      // global row in [0,2048)
  const int b   = row0 >> 8;
  const int ij0 = row0 & 255;
  const int i   = ij0 >> 4;
  const int j0  = ij0 & 15;             // 4 consecutive j, same i
  const int h    = threadIdx.x;
  const int wave = threadIdx.x >> 6;
  const int lane = threadIdx.x & 63;

  const float pv = P[(b*16 + i)*HDIM + h];
  float x[4];
  #pragma unroll
  for (int r = 0; r < 4; ++r) x[r] = pv + Q[(b*16 + j0 + r)*HDIM + h];

  // batched stats: 8 wave butterflies + LDS combine
  float s1[4], s2[4];
  #pragma unroll
  for (int r = 0; r < 4; ++r) { s1[r] = x[r]; s2[r] = x[r]*x[r]; }
  #pragma unroll
  for (int m = 32; m >= 1; m >>= 1) {
    #pragma unroll
    for (int r = 0; r < 4; ++r) {
      s1[r] += __shfl_xor(s1[r], m, 64);
      s2[r] += __shfl_xor(s2[r], m, 64);
    }
  }
  __shared__ float red[4][8];
  if (lane == 0) {
    #pragma unroll
    for (int r = 0; r < 4; ++r) { red[wave][2*r] = s1[r]; red[wave][2*r+1] = s2[r]; }
  }
  __syncthreads();

  __shared__ float rl[4][HDIM];
  #pragma unroll
  for (int r = 0; r < 4; ++r) {
    const float S1 = red[0][2*r] + red[1][2*r] + red[2][2*r] + red[3][2*r];
    const float S2 = red[0][2*r+1] + red[1][2*r+1] + red[2][2*r+1] + red[3][2*r+1];
    const float mean = S1 * (1.0f/256.0f);
    const float var  = S2 * (1.0f/256.0f) - mean*mean;
    const float rinv = rsqrtf(var + 1e-5f);
    rl[r][h] = fmaxf(fmaf((x[r] - mean)*rinv, g1[h], be1[h]), 0.0f);
  }
  __syncthreads();

  const float bb = b2[h];
  float acc[4] = {bb, bb, bb, bb};
  for (int k = 0; k < HDIM; k += 4) {
    const float4 r0 = *(const float4*)&rl[0][k];
    const float4 r1 = *(const float4*)&rl[1][k];
    const float4 r2 = *(const float4*)&rl[2][k];
    const float4 r3 = *(const float4*)&rl[3][k];
    const float w0 = W2[(k+0)*HDIM + h];
    const float w1 = W2[(k+1)*HDIM + h];
    const float w2 = W2[(k+2)*HDIM + h];
    const float w3 = W2[(k+3)*HDIM + h];
    acc[0] = fmaf(r0.x,w0, fmaf(r0.y,w1, fmaf(r0.z,w2, fmaf(r0.w,w3, acc[0]))));
    acc[1] = fmaf(r1.x,w0, fmaf(r1.y,w1, fmaf(r1.z,w2, fmaf(r1.w,w3, acc[1]))));
    acc[2] = fmaf(r2.x,w0, fmaf(r2.y,w1, fmaf(r2.z,w2, fmaf(r2.w,w3, acc[2]))));
    acc[3] = fmaf(r3.x,w0, fmaf(r3.y,w1, fmaf(r3.z,w2, fmaf(r3.w,w3, acc[3]))));
  }
  const float* relRow = rel + (b*16 + i)*16;
  #pragma unroll
  for (int r = 0; r < 4; ++r) {
    const float mask = (relRow[j0 + r] > 0.0f) ? 1.0f : 0.0f;
    out[(b*256 + ij0 + r)*HDIM + h] = acc[r] * mask;
  }
}

// ---------------------------------------------------------------------------
// K3: SA = src_rel @ Wa ; TB = tgt_rel @ Wb + map_b1 (4 rows/block).
// Epilogue: per-row sum & sumsq (for separable LN stats).
// ---------------------------------------------------------------------------
__global__ __launch_bounds__(256) void k_pairproj(
    const float* __restrict__ srel, const float* __restrict__ trel,
    const float* __restrict__ mapW1, const float* __restrict__ mapb1,
    float* __restrict__ SA, float* __restrict__ TB,
    float* __restrict__ rsS, float* __restrict__ qsS,
    float* __restrict__ rsT, float* __restrict__ qsT)
{
  const int which = blockIdx.y;        // 0: SA, 1: TB
  const int r0 = blockIdx.x * 4;       // 2048 rows total
  const int h  = threadIdx.x;
  const int wave = threadIdx.x >> 6;
  const int lane = threadIdx.x & 63;

  const float* A = which ? trel : srel;
  const float* W = which ? (mapW1 + EDIM*HDIM) : mapW1;

  __shared__ float arow[4][EDIM];
  #pragma unroll
  for (int r = 0; r < 4; ++r) arow[r][h] = A[(r0 + r)*EDIM + h];
  __syncthreads();

  float acc0, acc1, acc2, acc3;
  acc0 = acc1 = acc2 = acc3 = which ? mapb1[h] : 0.0f;
  #pragma unroll 4
  for (int d = 0; d < EDIM; ++d) {
    const float wv = W[d*HDIM + h];
    acc0 = fmaf(arow[0][d], wv, acc0);
    acc1 = fmaf(arow[1][d], wv, acc1);
    acc2 = fmaf(arow[2][d], wv, acc2);
    acc3 = fmaf(arow[3][d], wv, acc3);
  }
  float* out = which ? TB : SA;
  out[(r0+0)*HDIM + h] = acc0;
  out[(r0+1)*HDIM + h] = acc1;
  out[(r0+2)*HDIM + h] = acc2;
  out[(r0+3)*HDIM + h] = acc3;

  // row stats
  float s1[4] = {acc0, acc1, acc2, acc3};
  float s2[4] = {acc0*acc0, acc1*acc1, acc2*acc2, acc3*acc3};
  #pragma unroll
  for (int m = 32; m >= 1; m >>= 1) {
    #pragma unroll
    for (int r = 0; r < 4; ++r) {
      s1[r] += __shfl_xor(s1[r], m, 64);
      s2[r] += __shfl_xor(s2[r], m, 64);
    }
  }
  __shared__ float red[4][8];
  if (lane == 0) {
    #pragma unroll
    for (int r = 0; r < 4; ++r) { red[wave][2*r] = s1[r]; red[wave][2*r+1] = s2[r]; }
  }
  __syncthreads();
  if (threadIdx.x < 8) {
    const float v = red[0][threadIdx.x] + red[1][threadIdx.x] +
                    red[2][threadIdx.x] + red[3][threadIdx.x];
    const int r = threadIdx.x >> 1;
    float* rs = which ? rsT : rsS;
    float* qs = which ? qsT : qsS;
    if (threadIdx.x & 1) qs[r0 + r] = v; else rs[r0 + r] = v;
  }
}

// ---------------------------------------------------------------------------
// K3b: cross GEMM G[b,s,t] = SA[b,s,:].TB[b,t,:], fused into per-pair
// (mean, rinv) output. 32x32 tile per block, K chunked by 64 in LDS.
// ---------------------------------------------------------------------------
__global__ __launch_bounds__(256) void k_cross(
    const float* __restrict__ SA, const float* __restrict__ TB,
    const float* __restrict__ rsS, const float* __restrict__ qsS,
    const float* __restrict__ rsT, const float* __restrict__ qsT,
    float2* __restrict__ MR)
{
  const int b  = blockIdx.z;
  const int s0 = blockIdx.y * 32;
  const int t0 = blockIdx.x * 32;
  const int tx = threadIdx.x & 15;
  const int ty = threadIdx.x >> 4;

  const float* SAb = SA + (b*256 + s0)*HDIM;
  const float* TBb = TB + (b*256 + t0)*HDIM;

  __shared__ float As[32][68], Bs[32][68];
  float acc00 = 0.f, acc01 = 0.f, acc10 = 0.f, acc11 = 0.f;

  const int lr = threadIdx.x >> 3;        // 0..31
  const int lc = (threadIdx.x & 7) * 8;   // 0..56

  for (int kk = 0; kk < HDIM; kk += 64) {
    *(float4*)&As[lr][lc]   = *(const float4*)&SAb[lr*HDIM + kk + lc];
    *(float4*)&As[lr][lc+4] = *(const float4*)&SAb[lr*HDIM + kk + lc + 4];
    *(float4*)&Bs[lr][lc]   = *(const float4*)&TBb[lr*HDIM + kk + lc];
    *(float4*)&Bs[lr][lc+4] = *(const float4*)&TBb[lr*HDIM + kk + lc + 4];
    __syncthreads();
    #pragma unroll
    for (int k = 0; k < 64; k += 4) {
      const float4 a0 = *(const float4*)&As[ty][k];
      const float4 a1 = *(const float4*)&As[ty+16][k];
      const float4 b0 = *(const float4*)&Bs[tx][k];
      const float4 b1 = *(const float4*)&Bs[tx+16][k];
      acc00 = fmaf(a0.x,b0.x, fmaf(a0.y,b0.y, fmaf(a0.z,b0.z, fmaf(a0.w,b0.w, acc00))));
      acc01 = fmaf(a0.x,b1.x, fmaf(a0.y,b1.y, fmaf(a0.z,b1.z, fmaf(a0.w,b1.w, acc01))));
      acc10 = fmaf(a1.x,b0.x, fmaf(a1.y,b0.y, fmaf(a1.z,b0.z, fmaf(a1.w,b0.w, acc10))));
      acc11 = fmaf(a1.x,b1.x, fmaf(a1.y,b1.y, fmaf(a1.z,b1.z, fmaf(a1.w,b1.w, acc11))));
    }
    __syncthreads();
  }

  const int base = b*256;
  #pragma unroll
  for (int i = 0; i < 2; ++i) {
    const int s = s0 + ty + 16*i;
    const float rs_s = rsS[base + s], qs_s = qsS[base + s];
    #pragma unroll
    for (int j = 0; j < 2; ++j) {
      const int t = t0 + tx + 16*j;
      const float G = (i==0) ? (j==0 ? acc00 : acc01) : (j==0 ? acc10 : acc11);
      const float mean = (rs_s + rsT[base + t]) * (1.0f/256.0f);
      const float e2   = (qs_s + qsT[base + t] + 2.0f*G) * (1.0f/256.0f);
      const float rinv = rsqrtf(e2 - mean*mean + 1e-5f);
      MR[(base + s)*256 + t] = make_float2(mean, rinv);
    }
  }
}

// ---------------------------------------------------------------------------
// K4: mapping score + softmax. Block = (b,s); wave w owns t in [64w,64w+64).
// LN stats come precomputed (MR) -> zero shuffles in the hot loop. The 64
// per-lane dot partials are reduced with ONE 64x64 butterfly reduce-scatter
// (63 shfl total); lane l ends holding score for t = 64w + l.
// map_b2 is constant over t -> cancels in softmax -> dropped.
// ---------------------------------------------------------------------------
__global__ __launch_bounds__(256) void k_mapscore(
    const float* __restrict__ SA, const float* __restrict__ TB,
    const float2* __restrict__ MR,
    const float* __restrict__ g, const float* __restrict__ be,
    const float* __restrict__ W2, float* __restrict__ out)
{
  const int bs   = blockIdx.x;         // b*256 + s
  const int b    = bs >> 8;
  const int wave = threadIdx.x >> 6;
  const int lane = threadIdx.x & 63;

  const float4 sa4 = *(const float4*)(SA + bs*HDIM + lane*4);
  const float4 g4  = *(const float4*)(g  + lane*4);
  const float4 be4 = *(const float4*)(be + lane*4);
  const float4 w24 = *(const float4*)(W2 + lane*4);
  const float*  TBb = TB + (b*256 + wave*64)*HDIM;
  const float2* MRb = MR + bs*256 + wave*64;

  float acc[64];
  #pragma unroll
  for (int it = 0; it < 64; ++it) {
    const float4 tb = *(const float4*)(TBb + it*HDIM + lane*4);
    const float2 mr = MRb[it];
    const float u0 = (sa4.x + tb.x - mr.x) * mr.y;
    const float u1 = (sa4.y + tb.y - mr.x) * mr.y;
    const float u2 = (sa4.z + tb.z - mr.x) * mr.y;
    const float u3 = (sa4.w + tb.w - mr.x) * mr.y;
    const float r0 = fmaxf(fmaf(u0, g4.x, be4.x), 0.0f);
    const float r1 = fmaxf(fmaf(u1, g4.y, be4.y), 0.0f);
    const float r2 = fmaxf(fmaf(u2, g4.z, be4.z), 0.0f);
    const float r3 = fmaxf(fmaf(u3, g4.w, be4.w), 0.0f);
    acc[it] = fmaf(r0, w24.x, fmaf(r1, w24.y, fmaf(r2, w24.z, r3*w24.w)));
  }

  // 64x64 butterfly reduce-scatter: lane l <- sum over lanes of acc[.] for t=l
  #pragma unroll
  for (int m = 32; m >= 1; m >>= 1) {
    const bool up = (lane & m) != 0;
    #pragma unroll
    for (int i = 0; i < m; ++i) {
      const float sent = up ? acc[i] : acc[i+m];
      const float recv = __shfl_xor(sent, m, 64);
      const float mine = up ? acc[i+m] : acc[i];
      acc[i] = mine + recv;
    }
  }
  const float score = acc[0];           // for t = wave*64 + lane

  // softmax over the block's 256 scores
  __shared__ float red[8];
  float mx = score;
  #pragma unroll
  for (int m = 32; m >= 1; m >>= 1) mx = fmaxf(mx, __shfl_xor(mx, m, 64));
  if (lane == 0) red[wave] = mx;
  __syncthreads();
  mx = fmaxf(fmaxf(red[0], red[1]), fmaxf(red[2], red[3]));
  const float e = __expf(score - mx);
  float se = waveAllSum(e);
  if (lane == 0) red[4 + wave] = se;
  __syncthreads();
  se = red[4] + red[5] + red[6] + red[7];
  out[bs*256 + threadIdx.x] = e / se;
}

// ---------------------------------------------------------------------------
// K5: corr score (no LN) + softmax over 16. One wave per (b,s). b2 cancels.
// ---------------------------------------------------------------------------
__global__ __launch_bounds__(64) void k_corr(
    const float* __restrict__ CA, const float* __restrict__ CB,
    const float* __restrict__ W2, float* __restrict__ out)
{
  const int bs   = blockIdx.x;    // b*16 + s
  const int b    = bs >> 4;
  const int lane = threadIdx.x;

  const float4 ca4 = *(const float4*)(CA + bs*HDIM + lane*4);
  const float4 w24 = *(const float4*)(W2 + lane*4);

  float sc[16];
  #pragma unroll
  for (int t = 0; t < 16; ++t) {
    const float4 cb4 = *(const float4*)(CB + (b*16 + t)*HDIM + lane*4);
    float p = fmaxf(ca4.x + cb4.x, 0.0f)*w24.x
            + fmaxf(ca4.y + cb4.y, 0.0f)*w24.y
            + fmaxf(ca4.z + cb4.z, 0.0f)*w24.z
            + fmaxf(ca4.w + cb4.w, 0.0f)*w24.w;
    p = waveAllSum(p);
    sc[t] = p;
  }
  float mx = sc[0];
  #pragma unroll
  for (int t = 1; t < 16; ++t) mx = fmaxf(mx, sc[t]);
  float se = 0.0f;
  #pragma unroll
  for (int t = 0; t < 16; ++t) { sc[t] = __expf(sc[t] - mx); se += sc[t]; }
  if (lane < 16) out[bs*16 + lane] = sc[lane] / se;
}

extern "C" void kernel_launch(void* const* d_in, const int* in_sizes, int n_in,
                              void* d_out, int out_size, void* d_ws, size_t ws_size,
                              hipStream_t stream) {
  const float* srcE  = (const float*)d_in[0];
  const float* srcR  = (const float*)d_in[1];
  const float* tgtE  = (const float*)d_in[2];
  const float* tgtR  = (const float*)d_in[3];
  const float* relW1 = (const float*)d_in[4];
  const float* relb1 = (const float*)d_in[5];
  const float* relg1 = (const float*)d_in[6];
  const float* relbe1= (const float*)d_in[7];
  const float* relW2 = (const float*)d_in[8];
  const float* relb2 = (const float*)d_in[9];
  const float* mapW1 = (const float*)d_in[10];
  const float* mapb1 = (const float*)d_in[11];
  const float* mapg  = (const float*)d_in[12];
  const float* mapbe = (const float*)d_in[13];
  const float* mapW2 = (const float*)d_in[14];
  const float* corW1 = (const float*)d_in[16];
  const float* corb1 = (const float*)d_in[17];
  const float* corW2 = (const float*)d_in[18];

  float* ws   = (float*)d_ws;
  float* Ps   = ws;                 // 32768 each
  float* Qs   = Ps   + 32768;
  float* Pt   = Qs   + 32768;
  float* Qt   = Pt   + 32768;
  float* CA   = Qt   + 32768;
  float* CB   = CA   + 32768;
  float* srel = CB   + 32768;       // 524288 each
  float* trel = srel + 524288;
  float* SA   = trel + 524288;
  float* TB   = SA   + 524288;

  // aliases over dead buffers:
  // stats (written by k_pairproj, after k_encode is done with Ps..Qt)
  float* rsS = Ps;          // 2048
  float* qsS = Ps + 2048;
  float* rsT = Ps + 4096;
  float* qsT = Ps + 6144;
  // MR (written by k_cross over srel+trel, dead after k_pairproj)
  float2* MR = (float2*)srel;   // 524288 float2 = 1,048,576 floats

  float* mapOut = (float*)d_out;        // 524288
  float* corOut = mapOut + 524288;      // 2048

  k_proj<<<dim3(128, 6), 256, 0, stream>>>(srcE, tgtE, relW1, relb1, corW1, corb1,
                                           Ps, Qs, Pt, Qt, CA, CB);
  k_encode<<<dim3(512, 2), 256, 0, stream>>>(Ps, Qs, srcR, srel,
                                             Pt, Qt, tgtR, trel,
                                             relg1, relbe1, relW2, relb2);
  k_pairproj<<<dim3(512, 2), 256, 0, stream>>>(srel, trel, mapW1, mapb1, SA, TB,
                                               rsS, qsS, rsT, qsT);
  k_cross<<<dim3(8, 8, 8), 256, 0, stream>>>(SA, TB, rsS, qsS, rsT, qsT, MR);
  k_mapscore<<<2048, 256, 0, stream>>>(SA, TB, MR, mapg, mapbe, mapW2, mapOut);
  k_corr<<<128, 64, 0, stream>>>(CA, CB, corW2, corOut);
}

// Round 3
// 98.826 us; speedup vs baseline: 1.8969x; 1.0113x over previous
//
#include <hip/hip_runtime.h>

#define EDIM 256
#define HDIM 256

__device__ __forceinline__ float waveAllSum(float v) {
  #pragma unroll
  for (int m = 32; m >= 1; m >>= 1) v += __shfl_xor(v, m, 64);
  return v;
}

// ---------------------------------------------------------------------------
// K1: six row-matmuls, 8 rows/block (grid 16x6): P/Q projections for
// rel-encode and CA/CB for corr. Biases folded: rel_b1 -> P, cor_b1 -> CB.
// 8 rows/block cuts W L2-traffic to 24.5 MB total.
// ---------------------------------------------------------------------------
__global__ __launch_bounds__(256) void k_proj(
    const float* __restrict__ srcE, const float* __restrict__ tgtE,
    const float* __restrict__ relW1, const float* __restrict__ relb1,
    const float* __restrict__ corW1, const float* __restrict__ corb1,
    float* __restrict__ Ps, float* __restrict__ Qs,
    float* __restrict__ Pt, float* __restrict__ Qt,
    float* __restrict__ CA, float* __restrict__ CB)
{
  const int which = blockIdx.y;       // 0..5
  const int row0  = blockIdx.x * 8;   // 0..127 rows per 'which'
  const int h     = threadIdx.x;

  const float* A; const float* W; const float* bias; float* out;
  if (which == 0)      { A = srcE; W = relW1;              bias = relb1;   out = Ps; }
  else if (which == 1) { A = srcE; W = relW1 + EDIM*HDIM;  bias = nullptr; out = Qs; }
  else if (which == 2) { A = tgtE; W = relW1;              bias = relb1;   out = Pt; }
  else if (which == 3) { A = tgtE; W = relW1 + EDIM*HDIM;  bias = nullptr; out = Qt; }
  else if (which == 4) { A = srcE; W = corW1;              bias = nullptr; out = CA; }
  else                 { A = tgtE; W = corW1 + EDIM*HDIM;  bias = corb1;   out = CB; }

  __shared__ float arow[8][EDIM];
  #pragma unroll
  for (int r = 0; r < 8; ++r) arow[r][h] = A[(row0 + r)*EDIM + h];
  __syncthreads();

  float acc[8];
  const float init = bias ? bias[h] : 0.0f;
  #pragma unroll
  for (int r = 0; r < 8; ++r) acc[r] = init;

  for (int d = 0; d < EDIM; d += 4) {
    const float w0 = W[(d+0)*HDIM + h];
    const float w1 = W[(d+1)*HDIM + h];
    const float w2 = W[(d+2)*HDIM + h];
    const float w3 = W[(d+3)*HDIM + h];
    #pragma unroll
    for (int r = 0; r < 8; ++r) {
      const float4 av = *(const float4*)&arow[r][d];
      acc[r] = fmaf(av.x,w0, fmaf(av.y,w1, fmaf(av.z,w2, fmaf(av.w,w3, acc[r]))));
    }
  }
  #pragma unroll
  for (int r = 0; r < 8; ++r) out[(row0 + r)*HDIM + h] = acc[r];
}

// ---------------------------------------------------------------------------
// K2: fused rel-encode, 8 rows (same b,i; consecutive j) per block:
// x = P[b,i,:]+Q[b,j,:]; LN; relu; @rel_W2 + b2; mask. 8x W2 reuse.
// ---------------------------------------------------------------------------
__global__ __launch_bounds__(256) void k_encode(
    const float* __restrict__ Ps, const float* __restrict__ Qs,
    const float* __restrict__ relS, float* __restrict__ outS,
    const float* __restrict__ Pt, const float* __restrict__ Qt,
    const float* __restrict__ relT, float* __restrict__ outT,
    const float* __restrict__ g1, const float* __restrict__ be1,
    const float* __restrict__ W2, const float* __restrict__ b2)
{
  const int side = blockIdx.y;
  const float* P   = side ? Pt   : Ps;
  const float* Q   = side ? Qt   : Qs;
  const float* rel = side ? relT : relS;
  float* out       = side ? outT : outS;

  const int row0 = blockIdx.x * 8;      // [0,2048)
  const int b   = row0 >> 8;
  const int ij0 = row0 & 255;
  const int i   = ij0 >> 4;
  const int j0  = ij0 & 15;             // 8 consecutive j, same i
  const int h    = threadIdx.x;
  const int wave = threadIdx.x >> 6;
  const int lane = threadIdx.x & 63;

  const float pv = P[(b*16 + i)*HDIM + h];
  float x[8];
  #pragma unroll
  for (int r = 0; r < 8; ++r) x[r] = pv + Q[(b*16 + j0 + r)*HDIM + h];

  float s1[8], s2[8];
  #pragma unroll
  for (int r = 0; r < 8; ++r) { s1[r] = x[r]; s2[r] = x[r]*x[r]; }
  #pragma unroll
  for (int m = 32; m >= 1; m >>= 1) {
    #pragma unroll
    for (int r = 0; r < 8; ++r) {
      s1[r] += __shfl_xor(s1[r], m, 64);
      s2[r] += __shfl_xor(s2[r], m, 64);
    }
  }
  __shared__ float red[4][16];
  if (lane == 0) {
    #pragma unroll
    for (int r = 0; r < 8; ++r) { red[wave][2*r] = s1[r]; red[wave][2*r+1] = s2[r]; }
  }
  __syncthreads();

  __shared__ float rl[8][HDIM];
  #pragma unroll
  for (int r = 0; r < 8; ++r) {
    const float S1 = red[0][2*r] + red[1][2*r] + red[2][2*r] + red[3][2*r];
    const float S2 = red[0][2*r+1] + red[1][2*r+1] + red[2][2*r+1] + red[3][2*r+1];
    const float mean = S1 * (1.0f/256.0f);
    const float var  = S2 * (1.0f/256.0f) - mean*mean;
    const float rinv = rsqrtf(var + 1e-5f);
    rl[r][h] = fmaxf(fmaf((x[r] - mean)*rinv, g1[h], be1[h]), 0.0f);
  }
  __syncthreads();

  const float bb = b2[h];
  float acc[8];
  #pragma unroll
  for (int r = 0; r < 8; ++r) acc[r] = bb;

  for (int k = 0; k < HDIM; k += 4) {
    const float w0 = W2[(k+0)*HDIM + h];
    const float w1 = W2[(k+1)*HDIM + h];
    const float w2 = W2[(k+2)*HDIM + h];
    const float w3 = W2[(k+3)*HDIM + h];
    #pragma unroll
    for (int r = 0; r < 8; ++r) {
      const float4 rv = *(const float4*)&rl[r][k];
      acc[r] = fmaf(rv.x,w0, fmaf(rv.y,w1, fmaf(rv.z,w2, fmaf(rv.w,w3, acc[r]))));
    }
  }
  const float* relRow = rel + (b*16 + i)*16;
  #pragma unroll
  for (int r = 0; r < 8; ++r) {
    const float mask = (relRow[j0 + r] > 0.0f) ? 1.0f : 0.0f;
    out[(b*256 + ij0 + r)*HDIM + h] = acc[r] * mask;
  }
}

// ---------------------------------------------------------------------------
// K3: which=0: SA = src_rel @ Wa (+ per-row sum/sumsq stats).
//     which=1: TBt[b][h][t] = (tgt_rel @ Wb + map_b1)^T  (LDS transpose).
// 8 rows/block.
// ---------------------------------------------------------------------------
__global__ __launch_bounds__(256) void k_pairproj(
    const float* __restrict__ srel, const float* __restrict__ trel,
    const float* __restrict__ mapW1, const float* __restrict__ mapb1,
    float* __restrict__ SA, float* __restrict__ TBt,
    float* __restrict__ rsS, float* __restrict__ qsS)
{
  const int which = blockIdx.y;        // 0: SA, 1: TBt
  const int r0 = blockIdx.x * 8;       // 2048 rows
  const int h  = threadIdx.x;
  const int wave = threadIdx.x >> 6;
  const int lane = threadIdx.x & 63;

  const float* A = which ? trel : srel;
  const float* W = which ? (mapW1 + EDIM*HDIM) : mapW1;

  __shared__ float tile[8][EDIM];
  #pragma unroll
  for (int r = 0; r < 8; ++r) tile[r][h] = A[(r0 + r)*EDIM + h];
  __syncthreads();

  float acc[8];
  const float init = which ? mapb1[h] : 0.0f;
  #pragma unroll
  for (int r = 0; r < 8; ++r) acc[r] = init;

  for (int d = 0; d < EDIM; d += 4) {
    const float w0 = W[(d+0)*HDIM + h];
    const float w1 = W[(d+1)*HDIM + h];
    const float w2 = W[(d+2)*HDIM + h];
    const float w3 = W[(d+3)*HDIM + h];
    #pragma unroll
    for (int r = 0; r < 8; ++r) {
      const float4 av = *(const float4*)&tile[r][d];
      acc[r] = fmaf(av.x,w0, fmaf(av.y,w1, fmaf(av.z,w2, fmaf(av.w,w3, acc[r]))));
    }
  }

  if (which == 0) {
    #pragma unroll
    for (int r = 0; r < 8; ++r) SA[(r0 + r)*HDIM + h] = acc[r];
    // per-row sum & sumsq
    float s1[8], s2[8];
    #pragma unroll
    for (int r = 0; r < 8; ++r) { s1[r] = acc[r]; s2[r] = acc[r]*acc[r]; }
    #pragma unroll
    for (int m = 32; m >= 1; m >>= 1) {
      #pragma unroll
      for (int r = 0; r < 8; ++r) {
        s1[r] += __shfl_xor(s1[r], m, 64);
        s2[r] += __shfl_xor(s2[r], m, 64);
      }
    }
    __shared__ float red[4][16];
    if (lane == 0) {
      #pragma unroll
      for (int r = 0; r < 8; ++r) { red[wave][2*r] = s1[r]; red[wave][2*r+1] = s2[r]; }
    }
    __syncthreads();
    if (threadIdx.x < 16) {
      const float v = red[0][threadIdx.x] + red[1][threadIdx.x] +
                      red[2][threadIdx.x] + red[3][threadIdx.x];
      const int r = threadIdx.x >> 1;
      if (threadIdx.x & 1) qsS[r0 + r] = v; else rsS[r0 + r] = v;
    }
  } else {
    __syncthreads();                    // everyone done reading tile
    #pragma unroll
    for (int r = 0; r < 8; ++r) tile[r][h] = acc[r];
    __syncthreads();
    const int b = r0 >> 8, tcol = r0 & 255;
    float* dst = TBt + (((b<<8) + h)<<8) + tcol;   // TBt[b][h][tcol..tcol+8)
    const float4 v0 = make_float4(tile[0][h], tile[1][h], tile[2][h], tile[3][h]);
    const float4 v1 = make_float4(tile[4][h], tile[5][h], tile[6][h], tile[7][h]);
    *(float4*)dst = v0;
    *(float4*)(dst + 4) = v1;
  }
}

// ---------------------------------------------------------------------------
// K4: fused scores.
// Blocks [0,512): mapping. Block = (b, 4 s). Wave w owns t in [64w,64w+64);
//   lane l owns t=64w+l for all 4 s. Pass 1 over h: per-t sum/sumsq + cross
//   dots G[s] (SA via uniform scalar loads). Pass 2: LN+relu+W2-dot, 5 VALU
//   per pair-element, zero shuffles / zero LDS in hot loops. Softmax via LDS.
// Blocks [512,544): corr scores, wave = one (b,s), softmax over 16.
// map_b2 / cor_b2 cancel in softmax -> dropped.
// ---------------------------------------------------------------------------
__global__ __launch_bounds__(256) void k_scores(
    const float* __restrict__ SA, const float* __restrict__ TBt,
    const float* __restrict__ rsS, const float* __restrict__ qsS,
    const float* __restrict__ g, const float* __restrict__ be,
    const float* __restrict__ W2,
    const float* __restrict__ CA, const float* __restrict__ CB,
    const float* __restrict__ cW2,
    float* __restrict__ mapOut, float* __restrict__ corOut)
{
  const int wave = threadIdx.x >> 6;
  const int lane = threadIdx.x & 63;

  if (blockIdx.x >= 512) {
    // ---- corr: 32 blocks x 4 waves; wave handles one bs in [0,128) ----
    const int bs = (blockIdx.x - 512)*4 + wave;
    const int b  = bs >> 4;
    const float4 ca4 = *(const float4*)(CA + bs*HDIM + lane*4);
    const float4 w24 = *(const float4*)(cW2 + lane*4);
    float sc[16];
    #pragma unroll
    for (int t = 0; t < 16; ++t) {
      const float4 cb4 = *(const float4*)(CB + (b*16 + t)*HDIM + lane*4);
      float p = fmaxf(ca4.x + cb4.x, 0.0f)*w24.x
              + fmaxf(ca4.y + cb4.y, 0.0f)*w24.y
              + fmaxf(ca4.z + cb4.z, 0.0f)*w24.z
              + fmaxf(ca4.w + cb4.w, 0.0f)*w24.w;
      sc[t] = waveAllSum(p);
    }
    float mx = sc[0];
    #pragma unroll
    for (int t = 1; t < 16; ++t) mx = fmaxf(mx, sc[t]);
    float se = 0.0f;
    #pragma unroll
    for (int t = 0; t < 16; ++t) { sc[t] = __expf(sc[t] - mx); se += sc[t]; }
    if (lane < 16) corOut[bs*16 + lane] = sc[lane] / se;
    return;
  }

  // ---- mapping ----
  const int b  = blockIdx.x >> 6;
  const int s0 = (blockIdx.x & 63) * 4;
  const int t  = (wave << 6) + lane;

  const float* TBb = TBt + ((b<<8) << 8);          // [h][256]
  const float* sa0 = SA + ((b<<8) + s0)*HDIM;      // uniform-addr rows
  const float* sa1 = sa0 + HDIM;
  const float* sa2 = sa1 + HDIM;
  const float* sa3 = sa2 + HDIM;

  // pass 1: per-t stats + cross dots
  float rs_t = 0.f, qs_t = 0.f;
  float G0 = 0.f, G1 = 0.f, G2 = 0.f, G3 = 0.f;
  #pragma unroll 4
  for (int h = 0; h < HDIM; ++h) {
    const float tb = TBb[(h<<8) + t];
    rs_t += tb;
    qs_t = fmaf(tb, tb, qs_t);
    G0 = fmaf(sa0[h], tb, G0);
    G1 = fmaf(sa1[h], tb, G1);
    G2 = fmaf(sa2[h], tb, G2);
    G3 = fmaf(sa3[h], tb, G3);
  }

  float al[4], bt[4];
  {
    const float Gv[4] = {G0, G1, G2, G3};
    #pragma unroll
    for (int si = 0; si < 4; ++si) {
      const float mean = (rsS[(b<<8) + s0 + si] + rs_t) * (1.0f/256.0f);
      const float e2   = (qsS[(b<<8) + s0 + si] + qs_t + 2.0f*Gv[si]) * (1.0f/256.0f);
      const float rinv = rsqrtf(e2 - mean*mean + 1e-5f);
      al[si] = rinv;
      bt[si] = -mean * rinv;
    }
  }

  // pass 2: LN + relu + dot(W2)
  float a0 = 0.f, a1 = 0.f, a2 = 0.f, a3 = 0.f;
  #pragma unroll 4
  for (int h = 0; h < HDIM; ++h) {
    const float tb  = TBb[(h<<8) + t];
    const float gh  = g[h], beh = be[h], wh = W2[h];
    float u, r;
    u = fmaf(tb, al[0], fmaf(sa0[h], al[0], bt[0]));
    r = fmaxf(fmaf(u, gh, beh), 0.0f); a0 = fmaf(r, wh, a0);
    u = fmaf(tb, al[1], fmaf(sa1[h], al[1], bt[1]));
    r = fmaxf(fmaf(u, gh, beh), 0.0f); a1 = fmaf(r, wh, a1);
    u = fmaf(tb, al[2], fmaf(sa2[h], al[2], bt[2]));
    r = fmaxf(fmaf(u, gh, beh), 0.0f); a2 = fmaf(r, wh, a2);
    u = fmaf(tb, al[3], fmaf(sa3[h], al[3], bt[3]));
    r = fmaxf(fmaf(u, gh, beh), 0.0f); a3 = fmaf(r, wh, a3);
  }

  // softmax over t (256) for each of the 4 s
  __shared__ float sc[4][256];
  sc[0][t] = a0; sc[1][t] = a1; sc[2][t] = a2; sc[3][t] = a3;
  __syncthreads();

  // wave w handles s = s0 + w
  float v0 = sc[wave][lane];
  float v1 = sc[wave][lane + 64];
  float v2 = sc[wave][lane + 128];
  float v3 = sc[wave][lane + 192];
  float mx = fmaxf(fmaxf(v0, v1), fmaxf(v2, v3));
  #pragma unroll
  for (int m = 32; m >= 1; m >>= 1) mx = fmaxf(mx, __shfl_xor(mx, m, 64));
  const float e0 = __expf(v0 - mx), e1 = __expf(v1 - mx);
  const float e2 = __expf(v2 - mx), e3 = __expf(v3 - mx);
  const float se = waveAllSum(e0 + e1 + e2 + e3);
  const float inv = 1.0f / se;
  float* orow = mapOut + ((b<<8) + s0 + wave)*256;
  orow[lane]       = e0 * inv;
  orow[lane + 64]  = e1 * inv;
  orow[lane + 128] = e2 * inv;
  orow[lane + 192] = e3 * inv;
}

extern "C" void kernel_launch(void* const* d_in, const int* in_sizes, int n_in,
                              void* d_out, int out_size, void* d_ws, size_t ws_size,
                              hipStream_t stream) {
  const float* srcE  = (const float*)d_in[0];
  const float* srcR  = (const float*)d_in[1];
  const float* tgtE  = (const float*)d_in[2];
  const float* tgtR  = (const float*)d_in[3];
  const float* relW1 = (const float*)d_in[4];
  const float* relb1 = (const float*)d_in[5];
  const float* relg1 = (const float*)d_in[6];
  const float* relbe1= (const float*)d_in[7];
  const float* relW2 = (const float*)d_in[8];
  const float* relb2 = (const float*)d_in[9];
  const float* mapW1 = (const float*)d_in[10];
  const float* mapb1 = (const float*)d_in[11];
  const float* mapg  = (const float*)d_in[12];
  const float* mapbe = (const float*)d_in[13];
  const float* mapW2 = (const float*)d_in[14];
  const float* corW1 = (const float*)d_in[16];
  const float* corb1 = (const float*)d_in[17];
  const float* corW2 = (const float*)d_in[18];

  float* ws   = (float*)d_ws;
  float* Ps   = ws;                 // 32768 each
  float* Qs   = Ps   + 32768;
  float* Pt   = Qs   + 32768;
  float* Qt   = Pt   + 32768;
  float* CA   = Qt   + 32768;
  float* CB   = CA   + 32768;
  float* srel = CB   + 32768;       // 524288 each
  float* trel = srel + 524288;
  float* SA   = trel + 524288;
  float* TBt  = SA   + 524288;

  // stats alias over Ps (dead after k_encode)
  float* rsS = Ps;          // 2048
  float* qsS = Ps + 2048;   // 2048

  float* mapOut = (float*)d_out;        // 524288
  float* corOut = mapOut + 524288;      // 2048

  k_proj<<<dim3(16, 6), 256, 0, stream>>>(srcE, tgtE, relW1, relb1, corW1, corb1,
                                          Ps, Qs, Pt, Qt, CA, CB);
  k_encode<<<dim3(256, 2), 256, 0, stream>>>(Ps, Qs, srcR, srel,
                                             Pt, Qt, tgtR, trel,
                                             relg1, relbe1, relW2, relb2);
  k_pairproj<<<dim3(256, 2), 256, 0, stream>>>(srel, trel, mapW1, mapb1,
                                               SA, TBt, rsS, qsS);
  k_scores<<<544, 256, 0, stream>>>(SA, TBt, rsS, qsS, mapg, mapbe, mapW2,
                                    CA, CB, corW2, mapOut, corOut);
}